// Round 4
// baseline (158.966 us; speedup 1.0000x reference)
//
#include <hip/hip_runtime.h>

#define D 64
#define KCODES 512
#define BLOCK 1024       // 16 waves
#define RPB 256          // rows/block: 16 waves x 16 rows -> grid 512 = 2 blocks/CU
#define SSTR 513         // hi-seg stride in 16B units: 512+1 pad breaks seg-bank collision
#define HI_UNITS (8 * SSTR)                    // 4104 x 16B = 65,664 B hi LDS image
#define LO_OFF   HI_UNITS                      // lo frag buffer start (16B units)
#define LO_UNITS (KCODES * 8)                  // 4096 x 16B = 65,536 B
#define CC_OFF   ((HI_UNITS + LO_UNITS) * 16)  // byte offset of cc[512] in ws

typedef short  short4_ __attribute__((ext_vector_type(4)));
typedef short  short8  __attribute__((ext_vector_type(8)));
typedef float  f32x4   __attribute__((ext_vector_type(4)));

__device__ __forceinline__ unsigned short bf16rne(float f) {
    union { float f; unsigned u; } a; a.f = f;
    unsigned r = a.u + 0x7FFFu + ((a.u >> 16) & 1u);
    return (unsigned short)(r >> 16);
}
__device__ __forceinline__ void bf16_split(float f, unsigned short& h, unsigned short& l) {
    h = bf16rne(f);
    union { unsigned u; float f; } b; b.u = (unsigned)h << 16;
    l = bf16rne(f - b.f);
}

// Prep: split codebook once, globally. Writes to ws:
//   [0, 65664)        : hi image of (-2c) bf16, EXACT LDS layout [seg][SSTR][16B]
//                       (main stages it with a dumb linear copy — no VALU, no regs)
//   [65664, 131200)   : lo residual in per-ct FRAGMENT layout: unit
//                       u = ct*128 + sg*64 + quad*16 + col  == bytes that
//                       s_cbl[(sg*4+quad)*SSTR + ct*16+col] held in r0
//   [131200, 133248)  : cc[512] fp32
// Same validated split math as r0's prologue A; only the destinations differ.
__global__ __launch_bounds__(256) void vq_prep(const float* __restrict__ cb,
                                               float* __restrict__ ws) {
    const int e  = blockIdx.x * 256 + threadIdx.x;   // 0..8191 = (code, db)
    const int k  = e >> 4;
    const int db = e & 15;
    const int seg = db >> 1, j0 = (db & 1) * 4;
    const float4 q = ((const float4*)cb)[e];
    short4_ hh, ll;
    {
        unsigned short h_, l_;
        bf16_split(-2.f * q.x, h_, l_); hh[0] = (short)h_; ll[0] = (short)l_;
        bf16_split(-2.f * q.y, h_, l_); hh[1] = (short)h_; ll[1] = (short)l_;
        bf16_split(-2.f * q.z, h_, l_); hh[2] = (short)h_; ll[2] = (short)l_;
        bf16_split(-2.f * q.w, h_, l_); hh[3] = (short)h_; ll[3] = (short)l_;
    }
    short* wss = (short*)ws;
    *(short4_*)(wss + (seg * SSTR + k) * 8 + j0) = hh;
    const int u = (k >> 4) * 128 + (seg >> 2) * 64 + (seg & 3) * 16 + (k & 15);
    *(short4_*)(wss + (LO_OFF + u) * 8 + j0) = ll;
    // cc via 16-lane shuffle tree (lane groups aligned: db == lane&15)
    float p = fmaf(q.x, q.x, 0.f);
    p = fmaf(q.y, q.y, p); p = fmaf(q.z, q.z, p); p = fmaf(q.w, q.w, p);
    p += __shfl_xor(p, 1); p += __shfl_xor(p, 2);
    p += __shfl_xor(p, 4); p += __shfl_xor(p, 8);
    if (db == 0) ((float*)((char*)ws + CC_OFF))[k] = p;
}

// Main: hi codebook in LDS (65.7 KB -> 70.8 KB total -> 2 blocks/CU = 32
// waves/CU, double r0-r2's 16), lo streamed from L1/L2-hot frag buffer,
// 1 row-tile per wave. Numerics identical to r0 (6-MFMA 3-term, tau=1e-3
// hedge, exact fp32 fallback).
__global__ __launch_bounds__(BLOCK, 8) void vq_main(const float* __restrict__ x,
                                                    const float* __restrict__ cb,
                                                    const float* __restrict__ ws,
                                                    float* __restrict__ out) {
    __shared__ short8 s_cbh[HI_UNITS];          // 65,664 B
    __shared__ float s_cc[KCODES];              // 2 KiB
    __shared__ float s_xx[RPB];
    __shared__ int   s_bi[RPB];
    __shared__ int   s_flag[RPB];
    __shared__ int   s_nflag;

    const int t    = threadIdx.x;
    const int w    = t >> 6;        // wave 0..15
    const int lane = t & 63;
    const int quad = lane >> 4;
    const int col  = lane & 15;
    const float4* xv4  = (const float4*)x;
    const float4* cbv4 = (const float4*)cb;

    if (t == 0) s_nflag = 0;

    // Stage hi image: linear 16B copy, coalesced, conflict-free. 5 iters.
    const short8* hi_g = (const short8*)ws;
    #pragma unroll
    for (int i = 0; i < 5; ++i) {
        const int u = i * BLOCK + t;
        if (u < HI_UNITS) s_cbh[u] = hi_g[u];
    }
    if (t < KCODES) s_cc[t] = ((const float*)((const char*)ws + CC_OFF))[t];

    // x prologue: 1 row-tile of 16 rows per wave (m = col), A-frag layout
    // d = kt*32 + quad*8 + j (validated), xx via quad-shuffle tree.
    short8 xh[2], xl[2];
    {
        const size_t row = (size_t)blockIdx.x * RPB + w * 16 + col;
        float ssq = 0.f;
        #pragma unroll
        for (int kt = 0; kt < 2; ++kt) {
            const float4 p0 = xv4[row * 16 + kt * 8 + quad * 2];
            const float4 p1 = xv4[row * 16 + kt * 8 + quad * 2 + 1];
            float v[8] = {p0.x, p0.y, p0.z, p0.w, p1.x, p1.y, p1.z, p1.w};
            short8 hh, ll;
            #pragma unroll
            for (int j = 0; j < 8; ++j) {
                unsigned short h, l;
                bf16_split(v[j], h, l);
                hh[j] = (short)h; ll[j] = (short)l;
                ssq = fmaf(v[j], v[j], ssq);
            }
            xh[kt] = hh; xl[kt] = ll;
        }
        ssq += __shfl_xor(ssq, 16);
        ssq += __shfl_xor(ssq, 32);
        if (quad == 0) s_xx[w * 16 + col] = ssq;
    }

    float best[4], second[4]; int bis[4];
    #pragma unroll
    for (int i = 0; i < 4; ++i) { best[i] = __builtin_inff(); second[i] = __builtin_inff(); bis[i] = 0; }

    __syncthreads();    // hi + cc + xx ready; k-loop barrier-free

    // k-loop: 2 ds_read_b128 (hi) + 2 coalesced global dwordx4 (lo, L1/L2-hot)
    // + 6-MFMA chain per ct. acc init = cck (xx shift dropped: argmin-order
    // invariant; fallback uses s_xx for true distances). unroll 2 -> two
    // independent acc chains in flight.
    const short8* lo_g = (const short8*)ws + LO_OFF;
    #pragma unroll 2
    for (int ct = 0; ct < KCODES / 16; ++ct) {
        const int k = ct * 16 + col;
        short8 ch0 = s_cbh[quad * SSTR + k];
        short8 ch1 = s_cbh[(4 + quad) * SSTR + k];
        short8 cl0 = lo_g[ct * 128 + lane];
        short8 cl1 = lo_g[ct * 128 + 64 + lane];
        const float cck = s_cc[k];
        f32x4 acc;
        #pragma unroll
        for (int r = 0; r < 4; ++r) acc[r] = cck;
        acc = __builtin_amdgcn_mfma_f32_16x16x32_bf16(xh[0], ch0, acc, 0, 0, 0);
        acc = __builtin_amdgcn_mfma_f32_16x16x32_bf16(xl[0], ch0, acc, 0, 0, 0);
        acc = __builtin_amdgcn_mfma_f32_16x16x32_bf16(xh[0], cl0, acc, 0, 0, 0);
        acc = __builtin_amdgcn_mfma_f32_16x16x32_bf16(xh[1], ch1, acc, 0, 0, 0);
        acc = __builtin_amdgcn_mfma_f32_16x16x32_bf16(xl[1], ch1, acc, 0, 0, 0);
        acc = __builtin_amdgcn_mfma_f32_16x16x32_bf16(xh[1], cl1, acc, 0, 0, 0);
        #pragma unroll
        for (int r = 0; r < 4; ++r) {
            const float dist = acc[r];
            second[r] = fminf(second[r], fmaxf(best[r], dist));
            if (dist < best[r]) { best[r] = dist; bis[r] = k; }
        }
    }

    // argmin across the 16 code-lanes per row (validated)
    #pragma unroll
    for (int r = 0; r < 4; ++r) {
        float b = best[r], s2 = second[r]; int bi = bis[r];
        #pragma unroll
        for (int off = 1; off < 16; off <<= 1) {
            float ob  = __shfl_xor(b, off);
            int   obi = __shfl_xor(bi, off);
            float os  = __shfl_xor(s2, off);
            s2 = fminf(fminf(s2, os), fmaxf(b, ob));
            if (ob < b || (ob == b && obi < bi)) { b = ob; bi = obi; }
        }
        if (col == 0) {
            const int row = w * 16 + quad * 4 + r;
            s_bi[row] = bi;
            if (s2 - b < 1e-3f) {
                int p = atomicAdd(&s_nflag, 1);
                s_flag[p] = row;
            }
        }
    }
    __syncthreads();

    // exact fp32 re-argmin, thin inverted form (validated; ~0.3% rows)
    const int nf = s_nflag;
    for (int i = w; i < nf; i += 16) {
        const int row = s_flag[i];
        const size_t gr = (size_t)blockIdx.x * RPB + row;
        const float xxv = s_xx[row];
        float dot0[8], dot1[8];
        #pragma unroll
        for (int kk = 0; kk < 8; ++kk) { dot0[kk] = 0.f; dot1[kk] = 0.f; }
        for (int db = 0; db < 16; ++db) {
            const float4 xqv = xv4[gr * 16 + db];
            #pragma unroll
            for (int kk = 0; kk < 8; ++kk) {
                const float4 cq = cbv4[(lane * 8 + kk) * 16 + db];
                dot0[kk] = fmaf(xqv.x, cq.x, dot0[kk]);
                dot1[kk] = fmaf(xqv.y, cq.y, dot1[kk]);
                dot0[kk] = fmaf(xqv.z, cq.z, dot0[kk]);
                dot1[kk] = fmaf(xqv.w, cq.w, dot1[kk]);
            }
        }
        float b = __builtin_inff(); int bi = 0;
        #pragma unroll
        for (int kk = 0; kk < 8; ++kk) {
            const int k = lane * 8 + kk;
            const float dist = (xxv - 2.f * (dot0[kk] + dot1[kk])) + s_cc[k];
            if (dist < b) { b = dist; bi = k; }
        }
        #pragma unroll
        for (int off = 1; off < 64; off <<= 1) {
            float ob  = __shfl_xor(b, off);
            int   obi = __shfl_xor(bi, off);
            if (ob < b || (ob == b && obi < bi)) { b = ob; bi = obi; }
        }
        if (lane == 0) s_bi[row] = bi;
    }
    __syncthreads();

    // coalesced gather+store (validated)
    float4* outv = (float4*)out + (size_t)blockIdx.x * (RPB * 16);
    #pragma unroll
    for (int j = 0; j < RPB * 16 / BLOCK; ++j) {
        const int f4 = j * BLOCK + t;
        const int r  = f4 >> 4;
        const int q  = f4 & 15;
        outv[f4] = cbv4[s_bi[r] * 16 + q];
    }
}

extern "C" void kernel_launch(void* const* d_in, const int* in_sizes, int n_in,
                              void* d_out, int out_size, void* d_ws, size_t ws_size,
                              hipStream_t stream) {
    const float* x  = (const float*)d_in[0];   // 131072 x 64
    const float* cb = (const float*)d_in[1];   // 512 x 64
    float* out = (float*)d_out;

    const int N = in_sizes[0] / D;             // 131072
    vq_prep<<<KCODES * 16 / 256, 256, 0, stream>>>(cb, (float*)d_ws);
    vq_main<<<N / RPB, BLOCK, 0, stream>>>(x, cb, (const float*)d_ws, out);
}

// Round 5
// 136.388 us; speedup vs baseline: 1.1655x; 1.1655x over previous
//
#include <hip/hip_runtime.h>

#define D 64
#define KCODES 512
#define BLOCK 1024       // 16 waves
#define RPB 256          // rows/block: 16 waves x 16 rows -> grid 512 = 2 blocks/CU
#define SSTR 513         // hi-seg stride in 16B units: 512+1 pad breaks seg-bank collision
#define HI_UNITS (8 * SSTR)                    // 4104 x 16B = 65,664 B hi LDS image
#define LO_OFF   HI_UNITS                      // lo frag buffer start (16B units)
#define LO_UNITS (KCODES * 8)                  // 4096 x 16B = 65,536 B
#define CC_OFF   ((HI_UNITS + LO_UNITS) * 16)  // byte offset of cc[512] in ws

typedef short  short4_ __attribute__((ext_vector_type(4)));
typedef short  short8  __attribute__((ext_vector_type(8)));
typedef float  f32x4   __attribute__((ext_vector_type(4)));

__device__ __forceinline__ unsigned short bf16rne(float f) {
    union { float f; unsigned u; } a; a.f = f;
    unsigned r = a.u + 0x7FFFu + ((a.u >> 16) & 1u);
    return (unsigned short)(r >> 16);
}
__device__ __forceinline__ void bf16_split(float f, unsigned short& h, unsigned short& l) {
    h = bf16rne(f);
    union { unsigned u; float f; } b; b.u = (unsigned)h << 16;
    l = bf16rne(f - b.f);
}

// Prep: split codebook once, globally. Writes to ws:
//   [0, 65664)        : hi image of (-2c) bf16, EXACT LDS layout [seg][SSTR][16B]
//                       (main stages it with a dumb linear copy — no VALU, no regs)
//   [65664, 131200)   : lo residual in per-ct FRAGMENT layout: unit
//                       u = ct*128 + sg*64 + quad*16 + col  == bytes that
//                       s_cbl[(sg*4+quad)*SSTR + ct*16+col] held in r0
//   [131200, 133248)  : cc[512] fp32
// Same validated split math as r0's prologue A; only the destinations differ.
__global__ __launch_bounds__(256) void vq_prep(const float* __restrict__ cb,
                                               float* __restrict__ ws) {
    const int e  = blockIdx.x * 256 + threadIdx.x;   // 0..8191 = (code, db)
    const int k  = e >> 4;
    const int db = e & 15;
    const int seg = db >> 1, j0 = (db & 1) * 4;
    const float4 q = ((const float4*)cb)[e];
    short4_ hh, ll;
    {
        unsigned short h_, l_;
        bf16_split(-2.f * q.x, h_, l_); hh[0] = (short)h_; ll[0] = (short)l_;
        bf16_split(-2.f * q.y, h_, l_); hh[1] = (short)h_; ll[1] = (short)l_;
        bf16_split(-2.f * q.z, h_, l_); hh[2] = (short)h_; ll[2] = (short)l_;
        bf16_split(-2.f * q.w, h_, l_); hh[3] = (short)h_; ll[3] = (short)l_;
    }
    short* wss = (short*)ws;
    *(short4_*)(wss + (seg * SSTR + k) * 8 + j0) = hh;
    const int u = (k >> 4) * 128 + (seg >> 2) * 64 + (seg & 3) * 16 + (k & 15);
    *(short4_*)(wss + (LO_OFF + u) * 8 + j0) = ll;
    // cc via 16-lane shuffle tree (lane groups aligned: db == lane&15)
    float p = fmaf(q.x, q.x, 0.f);
    p = fmaf(q.y, q.y, p); p = fmaf(q.z, q.z, p); p = fmaf(q.w, q.w, p);
    p += __shfl_xor(p, 1); p += __shfl_xor(p, 2);
    p += __shfl_xor(p, 4); p += __shfl_xor(p, 8);
    if (db == 0) ((float*)((char*)ws + CC_OFF))[k] = p;
}

// Main: hi codebook in LDS (70.8 KB total LDS -> 2 blocks/CU possible),
// lo streamed from L1/L2-hot frag buffer, 1 row-tile per wave.
// r5: launch_bounds (1024, 4) — r4's (1024, 8) squeezed the unified budget
// to 64 and the compiler partitioned 32 arch VGPR + AGPR, spilling ~70 MB
// of scratch traffic (WRITE_SIZE 69.5 MB). Cap 128 is the configuration
// that produced spill-free 64-reg allocation in r0; at <=64 total the HW
// still co-schedules 2 blocks/CU (residency is set by achieved alloc, not
// by the bound). Numerics identical to r0 (6-MFMA 3-term, tau=1e-3 hedge,
// exact fp32 fallback).
__global__ __launch_bounds__(BLOCK, 4) void vq_main(const float* __restrict__ x,
                                                    const float* __restrict__ cb,
                                                    const float* __restrict__ ws,
                                                    float* __restrict__ out) {
    __shared__ short8 s_cbh[HI_UNITS];          // 65,664 B
    __shared__ float s_cc[KCODES];              // 2 KiB
    __shared__ float s_xx[RPB];
    __shared__ int   s_bi[RPB];
    __shared__ int   s_flag[RPB];
    __shared__ int   s_nflag;

    const int t    = threadIdx.x;
    const int w    = t >> 6;        // wave 0..15
    const int lane = t & 63;
    const int quad = lane >> 4;
    const int col  = lane & 15;
    const float4* xv4  = (const float4*)x;
    const float4* cbv4 = (const float4*)cb;

    if (t == 0) s_nflag = 0;

    // Stage hi image: linear 16B copy, coalesced, conflict-free. 5 iters.
    const short8* hi_g = (const short8*)ws;
    #pragma unroll
    for (int i = 0; i < 5; ++i) {
        const int u = i * BLOCK + t;
        if (u < HI_UNITS) s_cbh[u] = hi_g[u];
    }
    if (t < KCODES) s_cc[t] = ((const float*)((const char*)ws + CC_OFF))[t];

    // x prologue: 1 row-tile of 16 rows per wave (m = col), A-frag layout
    // d = kt*32 + quad*8 + j (validated), xx via quad-shuffle tree.
    short8 xh[2], xl[2];
    {
        const size_t row = (size_t)blockIdx.x * RPB + w * 16 + col;
        float ssq = 0.f;
        #pragma unroll
        for (int kt = 0; kt < 2; ++kt) {
            const float4 p0 = xv4[row * 16 + kt * 8 + quad * 2];
            const float4 p1 = xv4[row * 16 + kt * 8 + quad * 2 + 1];
            float v[8] = {p0.x, p0.y, p0.z, p0.w, p1.x, p1.y, p1.z, p1.w};
            short8 hh, ll;
            #pragma unroll
            for (int j = 0; j < 8; ++j) {
                unsigned short h, l;
                bf16_split(v[j], h, l);
                hh[j] = (short)h; ll[j] = (short)l;
                ssq = fmaf(v[j], v[j], ssq);
            }
            xh[kt] = hh; xl[kt] = ll;
        }
        ssq += __shfl_xor(ssq, 16);
        ssq += __shfl_xor(ssq, 32);
        if (quad == 0) s_xx[w * 16 + col] = ssq;
    }

    float best[4], second[4]; int bis[4];
    #pragma unroll
    for (int i = 0; i < 4; ++i) { best[i] = __builtin_inff(); second[i] = __builtin_inff(); bis[i] = 0; }

    __syncthreads();    // hi + cc + xx ready; k-loop barrier-free

    // k-loop: 2 ds_read_b128 (hi) + 2 coalesced global dwordx4 (lo, L1/L2-hot)
    // + 6-MFMA chain per ct. acc init = cck (xx shift dropped: argmin-order
    // invariant; fallback uses s_xx for true distances). unroll 2 -> two
    // independent acc chains in flight.
    const short8* lo_g = (const short8*)ws + LO_OFF;
    #pragma unroll 2
    for (int ct = 0; ct < KCODES / 16; ++ct) {
        const int k = ct * 16 + col;
        short8 ch0 = s_cbh[quad * SSTR + k];
        short8 ch1 = s_cbh[(4 + quad) * SSTR + k];
        short8 cl0 = lo_g[ct * 128 + lane];
        short8 cl1 = lo_g[ct * 128 + 64 + lane];
        const float cck = s_cc[k];
        f32x4 acc;
        #pragma unroll
        for (int r = 0; r < 4; ++r) acc[r] = cck;
        acc = __builtin_amdgcn_mfma_f32_16x16x32_bf16(xh[0], ch0, acc, 0, 0, 0);
        acc = __builtin_amdgcn_mfma_f32_16x16x32_bf16(xl[0], ch0, acc, 0, 0, 0);
        acc = __builtin_amdgcn_mfma_f32_16x16x32_bf16(xh[0], cl0, acc, 0, 0, 0);
        acc = __builtin_amdgcn_mfma_f32_16x16x32_bf16(xh[1], ch1, acc, 0, 0, 0);
        acc = __builtin_amdgcn_mfma_f32_16x16x32_bf16(xl[1], ch1, acc, 0, 0, 0);
        acc = __builtin_amdgcn_mfma_f32_16x16x32_bf16(xh[1], cl1, acc, 0, 0, 0);
        #pragma unroll
        for (int r = 0; r < 4; ++r) {
            const float dist = acc[r];
            second[r] = fminf(second[r], fmaxf(best[r], dist));
            if (dist < best[r]) { best[r] = dist; bis[r] = k; }
        }
    }

    // argmin across the 16 code-lanes per row (validated)
    #pragma unroll
    for (int r = 0; r < 4; ++r) {
        float b = best[r], s2 = second[r]; int bi = bis[r];
        #pragma unroll
        for (int off = 1; off < 16; off <<= 1) {
            float ob  = __shfl_xor(b, off);
            int   obi = __shfl_xor(bi, off);
            float os  = __shfl_xor(s2, off);
            s2 = fminf(fminf(s2, os), fmaxf(b, ob));
            if (ob < b || (ob == b && obi < bi)) { b = ob; bi = obi; }
        }
        if (col == 0) {
            const int row = w * 16 + quad * 4 + r;
            s_bi[row] = bi;
            if (s2 - b < 1e-3f) {
                int p = atomicAdd(&s_nflag, 1);
                s_flag[p] = row;
            }
        }
    }
    __syncthreads();

    // exact fp32 re-argmin, thin inverted form (validated; ~0.3% rows)
    const int nf = s_nflag;
    for (int i = w; i < nf; i += 16) {
        const int row = s_flag[i];
        const size_t gr = (size_t)blockIdx.x * RPB + row;
        const float xxv = s_xx[row];
        float dot0[8], dot1[8];
        #pragma unroll
        for (int kk = 0; kk < 8; ++kk) { dot0[kk] = 0.f; dot1[kk] = 0.f; }
        for (int db = 0; db < 16; ++db) {
            const float4 xqv = xv4[gr * 16 + db];
            #pragma unroll
            for (int kk = 0; kk < 8; ++kk) {
                const float4 cq = cbv4[(lane * 8 + kk) * 16 + db];
                dot0[kk] = fmaf(xqv.x, cq.x, dot0[kk]);
                dot1[kk] = fmaf(xqv.y, cq.y, dot1[kk]);
                dot0[kk] = fmaf(xqv.z, cq.z, dot0[kk]);
                dot1[kk] = fmaf(xqv.w, cq.w, dot1[kk]);
            }
        }
        float b = __builtin_inff(); int bi = 0;
        #pragma unroll
        for (int kk = 0; kk < 8; ++kk) {
            const int k = lane * 8 + kk;
            const float dist = (xxv - 2.f * (dot0[kk] + dot1[kk])) + s_cc[k];
            if (dist < b) { b = dist; bi = k; }
        }
        #pragma unroll
        for (int off = 1; off < 64; off <<= 1) {
            float ob  = __shfl_xor(b, off);
            int   obi = __shfl_xor(bi, off);
            if (ob < b || (ob == b && obi < bi)) { b = ob; bi = obi; }
        }
        if (lane == 0) s_bi[row] = bi;
    }
    __syncthreads();

    // coalesced gather+store (validated)
    float4* outv = (float4*)out + (size_t)blockIdx.x * (RPB * 16);
    #pragma unroll
    for (int j = 0; j < RPB * 16 / BLOCK; ++j) {
        const int f4 = j * BLOCK + t;
        const int r  = f4 >> 4;
        const int q  = f4 & 15;
        outv[f4] = cbv4[s_bi[r] * 16 + q];
    }
}

extern "C" void kernel_launch(void* const* d_in, const int* in_sizes, int n_in,
                              void* d_out, int out_size, void* d_ws, size_t ws_size,
                              hipStream_t stream) {
    const float* x  = (const float*)d_in[0];   // 131072 x 64
    const float* cb = (const float*)d_in[1];   // 512 x 64
    float* out = (float*)d_out;

    const int N = in_sizes[0] / D;             // 131072
    vq_prep<<<KCODES * 16 / 256, 256, 0, stream>>>(cb, (float*)d_ws);
    vq_main<<<N / RPB, BLOCK, 0, stream>>>(x, cb, (const float*)d_ws, out);
}